// Round 2
// baseline (3057.339 us; speedup 1.0000x reference)
//
#include <hip/hip_runtime.h>
#include <cstdint>
#include <cstddef>

// Problem constants
#define T_SEQ 512
#define BATCH 128
#define HID   128
#define G4    512      // 4*H
#define NCLS  10

__device__ __forceinline__ float sigmoidf_(float x) {
    return 1.f / (1.f + __expf(-x));
}
__device__ __forceinline__ float tanhf_(float x) {
    // 2*sigmoid(2x)-1; saturates correctly without NaN
    return 2.f / (1.f + __expf(-2.f * x)) - 1.f;
}

// ---------------------------------------------------------------------------
// Chunked GEMM (NT): out[m*512+n] = sum_k A[row(m)][k] * W[n][k] + bih[n]+bhh[n]
// for m in [0, 128*Tc), n in [0,512).
// m -> (b = m>>tcshift, tt = m&(Tc-1)); global row grow = b*T_SEQ + tc0 + tt;
// physical A row = rows ? rows[grow] : grow  (token gather for layer 0).
// Output is chunk-local: xg[b][tt][gate].
// ---------------------------------------------------------------------------
#define BM 128
#define BN 128
#define BK 8

__global__ __launch_bounds__(256)
void gemm_xg(const float* __restrict__ A, const int* __restrict__ rows, int lda,
             const float* __restrict__ W, int K,
             const float* __restrict__ bih, const float* __restrict__ bhh,
             float* __restrict__ out, int tcshift, int tc0)
{
    const int ntn = G4 / BN;              // 4
    int tn = blockIdx.x % ntn;
    int tm = blockIdx.x / ntn;
    int m0 = tm * BM, n0 = tn * BN;
    int tid = threadIdx.x;

    __shared__ __align__(16) float As[BK][BM + 4];
    __shared__ __align__(16) float Ws[BK][BN + 4];

    // loader: 2 threads per row, 4 consecutive k each
    int lr = tid >> 1;
    int lk = (tid & 1) * 4;

    const float* arow;
    {
        int m  = m0 + lr;
        int b  = m >> tcshift;
        int tt = m & ((1 << tcshift) - 1);
        int grow = b * T_SEQ + tc0 + tt;
        int r = rows ? rows[grow] : grow;
        arow = A + (size_t)r * lda;
    }
    const float* wrow = W + (size_t)(n0 + lr) * K;

    int tx = tid & 15, ty = tid >> 4;
    float acc[8][8];
#pragma unroll
    for (int i = 0; i < 8; i++)
#pragma unroll
        for (int j = 0; j < 8; j++) acc[i][j] = 0.f;

    int nch = (K + BK - 1) / BK;
    for (int ch = 0; ch < nch; ch++) {
        int k0 = ch * BK;
#pragma unroll
        for (int u = 0; u < 4; u++) {
            int k = k0 + lk + u;
            As[lk + u][lr] = (k < K) ? arow[k] : 0.f;
            Ws[lk + u][lr] = (k < K) ? wrow[k] : 0.f;
        }
        __syncthreads();
#pragma unroll
        for (int kk = 0; kk < BK; kk++) {
            float a[8], b[8];
#pragma unroll
            for (int i = 0; i < 8; i++) a[i] = As[kk][ty * 8 + i];
#pragma unroll
            for (int j = 0; j < 8; j++) b[j] = Ws[kk][tx * 8 + j];
#pragma unroll
            for (int i = 0; i < 8; i++)
#pragma unroll
                for (int j = 0; j < 8; j++) acc[i][j] += a[i] * b[j];
        }
        __syncthreads();
    }

#pragma unroll
    for (int j = 0; j < 8; j++) {
        int n = n0 + tx * 8 + j;
        float bv = bih[n] + bhh[n];
#pragma unroll
        for (int i = 0; i < 8; i++) {
            int m = m0 + ty * 8 + i;
            out[(size_t)m * G4 + n] = acc[i][j] + bv;
        }
    }
}

// ---------------------------------------------------------------------------
// State-carrying LSTM recurrence over one time chunk.
// One workgroup per batch elem; 256 threads; thread j owns gate rows j, j+256
// with w_hh rows held in VGPRs (256 floats/thread -> __launch_bounds__(256,1)).
// h broadcast via LDS. (h,c) persisted in hstate/cstate between chunk launches.
// MODE 0: also write h into h0cat[b][t][dir*128+j]. MODE 1: state only.
// dir==1 scans the chunk (and the chunks, host-side) in reverse time order.
// ---------------------------------------------------------------------------
template <int MODE>
__global__ __launch_bounds__(256, 1)
void lstm_rec(const float* __restrict__ xg,    // [B][Tc][512] chunk-local
              const float* __restrict__ whh,
              float* __restrict__ hout,
              float* __restrict__ hstate, float* __restrict__ cstate,
              int Tc, int tc0, int dir, int first)
{
    int b = blockIdx.x;
    const float* xgb = xg + (size_t)b * Tc * G4;
    int j = threadIdx.x;  // 0..255 -> gate rows j and j+256

    float w0[128], w1[128];
    {
        const float* wr0 = whh + (size_t)j * HID;
        const float* wr1 = whh + (size_t)(j + 256) * HID;
#pragma unroll
        for (int k = 0; k < 128; k += 4) {
            float4 a = *(const float4*)(wr0 + k);
            w0[k] = a.x; w0[k + 1] = a.y; w0[k + 2] = a.z; w0[k + 3] = a.w;
            float4 c = *(const float4*)(wr1 + k);
            w1[k] = c.x; w1[k + 1] = c.y; w1[k + 2] = c.z; w1[k + 3] = c.w;
        }
    }

    __shared__ __align__(16) float h_s[HID];
    __shared__ __align__(16) float g_s[G4];
    float c_reg = 0.f;
    if (j < HID) {
        if (first) {
            h_s[j] = 0.f;
        } else {
            h_s[j]  = hstate[(size_t)b * HID + j];
            c_reg   = cstate[(size_t)b * HID + j];
        }
    }
    __syncthreads();

    for (int s = 0; s < Tc; s++) {
        int tt = (dir == 0) ? s : (Tc - 1 - s);
        const float* xp = xgb + (size_t)tt * G4;
        float xv0 = xp[j];
        float xv1 = xp[j + 256];

        float a0 = 0.f, a1 = 0.f;
#pragma unroll
        for (int k4 = 0; k4 < 32; k4++) {
            float4 h4 = ((const float4*)h_s)[k4];
            int k = k4 * 4;
            a0 += w0[k] * h4.x;     a1 += w1[k] * h4.x;
            a0 += w0[k + 1] * h4.y; a1 += w1[k + 1] * h4.y;
            a0 += w0[k + 2] * h4.z; a1 += w1[k + 2] * h4.z;
            a0 += w0[k + 3] * h4.w; a1 += w1[k + 3] * h4.w;
        }
        a0 += xv0;
        a1 += xv1;

        // gate rows: [0,128)=i sig, [128,256)=f sig, [256,384)=g tanh,
        // [384,512)=o sig. Branch is wave-uniform (j<128 splits at wave bound).
        float v0 = sigmoidf_(a0);
        float v1 = (j < 128) ? tanhf_(a1) : sigmoidf_(a1);
        g_s[j] = v0;
        g_s[j + 256] = v1;
        __syncthreads();

        if (j < HID) {
            float gi = g_s[j], gf = g_s[j + 128], gg = g_s[j + 256], go = g_s[j + 384];
            c_reg = gf * c_reg + gi * gg;
            float hv = go * tanhf_(c_reg);
            h_s[j] = hv;
            if (MODE == 0)
                hout[((size_t)b * T_SEQ + (tc0 + tt)) * 256 + dir * HID + j] = hv;
        }
        __syncthreads();
    }
    if (j < HID) {
        hstate[(size_t)b * HID + j] = h_s[j];
        cstate[(size_t)b * HID + j] = c_reg;
    }
}

// ---------------------------------------------------------------------------
// Finale: layer-1 reverse LSTM's t=T-1 output is a SINGLE step from zero
// state (reverse scan processes t=T-1 first), then the FC head.
// One workgroup per batch element. h1f final state read from hstate slot 2.
// ---------------------------------------------------------------------------
__global__ __launch_bounds__(512)
void final_k(const float* __restrict__ h0cat,
             const float* __restrict__ w_ih_r,
             const float* __restrict__ bih_r, const float* __restrict__ bhh_r,
             const float* __restrict__ h1f_last,
             const float* __restrict__ fc_w,
             const float* __restrict__ fc_b,
             float* __restrict__ out)
{
    int b = blockIdx.x;
    int j = threadIdx.x;  // 0..511
    __shared__ __align__(16) float hin[256];
    __shared__ __align__(16) float g_s[G4];
    __shared__ __align__(16) float hcat[256];

    if (j < 256) hin[j] = h0cat[((size_t)b * T_SEQ + (T_SEQ - 1)) * 256 + j];
    __syncthreads();

    float acc = bih_r[j] + bhh_r[j];
    const float* wr = w_ih_r + (size_t)j * 256;
#pragma unroll 8
    for (int k = 0; k < 256; k += 4) {
        float4 h4 = *(const float4*)&hin[k];
        float4 w4 = *(const float4*)&wr[k];
        acc += w4.x * h4.x + w4.y * h4.y + w4.z * h4.z + w4.w * h4.w;
    }
    float v = (j >= 256 && j < 384) ? tanhf_(acc) : sigmoidf_(acc);
    g_s[j] = v;
    if (j < 128) hcat[j] = h1f_last[(size_t)b * HID + j];
    __syncthreads();

    if (j < 128) {
        float gi = g_s[j], gg = g_s[j + 256], go = g_s[j + 384];
        float c = gi * gg;  // f * c0 with c0 = 0
        hcat[128 + j] = go * tanhf_(c);
    }
    __syncthreads();

    if (j < NCLS) {
        float a = fc_b[j];
        const float* fw = fc_w + (size_t)j * 256;
        for (int k = 0; k < 256; k++) a += fw[k] * hcat[k];
        out[(size_t)b * NCLS + j] = a;
    }
}

// ---------------------------------------------------------------------------
// Workspace layout (bytes):
//   [0,          64Mi)          h0cat   [B][T][256]       = 67,108,864
//   [64Mi,       64Mi+384Ki)    6 state slots (h,c)x3     =    393,216
//   [64Mi+384Ki, +256Ki*Tc)     xg chunk [B][Tc][512]
// Tc chosen as the largest in {512,...,32} fitting ws_size.
// ---------------------------------------------------------------------------
extern "C" void kernel_launch(void* const* d_in, const int* in_sizes, int n_in,
                              void* d_out, int out_size, void* d_ws, size_t ws_size,
                              hipStream_t stream)
{
    (void)in_sizes; (void)n_in; (void)out_size;

    const int*   x       = (const int*)  d_in[0];
    const float* emb     = (const float*)d_in[1];
    const float* wih_l0f = (const float*)d_in[2];
    const float* whh_l0f = (const float*)d_in[3];
    const float* bih_l0f = (const float*)d_in[4];
    const float* bhh_l0f = (const float*)d_in[5];
    const float* wih_l0r = (const float*)d_in[6];
    const float* whh_l0r = (const float*)d_in[7];
    const float* bih_l0r = (const float*)d_in[8];
    const float* bhh_l0r = (const float*)d_in[9];
    const float* wih_l1f = (const float*)d_in[10];
    const float* whh_l1f = (const float*)d_in[11];
    const float* bih_l1f = (const float*)d_in[12];
    const float* bhh_l1f = (const float*)d_in[13];
    const float* wih_l1r = (const float*)d_in[14];
    const float* whh_l1r = (const float*)d_in[15];  // unused (single step from h0=c0=0)
    const float* bih_l1r = (const float*)d_in[16];
    const float* bhh_l1r = (const float*)d_in[17];
    const float* fc_w    = (const float*)d_in[18];
    const float* fc_b    = (const float*)d_in[19];
    float* out = (float*)d_out;
    (void)whh_l1r;

    char* ws = (char*)d_ws;
    float* h0cat = (float*)ws;
    float* st    = (float*)(ws + (size_t)67108864);
    float* hst0 = st + 0 * 16384;
    float* cst0 = st + 1 * 16384;
    float* hst1 = st + 2 * 16384;
    float* cst1 = st + 3 * 16384;
    float* hst2 = st + 4 * 16384;
    float* cst2 = st + 5 * 16384;
    float* xgc  = (float*)(ws + (size_t)67108864 + 393216);

    // Pick largest chunk size that fits the workspace.
    const size_t base = (size_t)67108864 + 393216;
    int Tc = 512;
    while (Tc > 32 && base + (size_t)262144 * Tc > ws_size) Tc >>= 1;
    const int NC = T_SEQ / Tc;
    int tcshift = 0;
    while ((1 << tcshift) < Tc) tcshift++;
    const dim3 gemm_grid(Tc * (G4 / BN));  // (M/BM)*(512/BN) with M=128*Tc

    // Phase 1: layer-0 forward (chunks ascending)
    for (int ci = 0; ci < NC; ci++) {
        int tc0 = ci * Tc;
        gemm_xg<<<gemm_grid, 256, 0, stream>>>(
            emb, x, 300, wih_l0f, 300, bih_l0f, bhh_l0f, xgc, tcshift, tc0);
        lstm_rec<0><<<dim3(BATCH), 256, 0, stream>>>(
            xgc, whh_l0f, h0cat, hst0, cst0, Tc, tc0, 0, ci == 0);
    }

    // Phase 2: layer-0 reverse (chunks descending)
    for (int ci = NC - 1; ci >= 0; ci--) {
        int tc0 = ci * Tc;
        gemm_xg<<<gemm_grid, 256, 0, stream>>>(
            emb, x, 300, wih_l0r, 300, bih_l0r, bhh_l0r, xgc, tcshift, tc0);
        lstm_rec<0><<<dim3(BATCH), 256, 0, stream>>>(
            xgc, whh_l0r, h0cat, hst1, cst1, Tc, tc0, 1, ci == NC - 1);
    }

    // Phase 3: layer-1 forward (chunks ascending), state only
    for (int ci = 0; ci < NC; ci++) {
        int tc0 = ci * Tc;
        gemm_xg<<<gemm_grid, 256, 0, stream>>>(
            h0cat, nullptr, 256, wih_l1f, 256, bih_l1f, bhh_l1f, xgc, tcshift, tc0);
        lstm_rec<1><<<dim3(BATCH), 256, 0, stream>>>(
            xgc, whh_l1f, nullptr, hst2, cst2, Tc, tc0, 0, ci == 0);
    }

    // Phase 4: layer-1 reverse single step + FC head
    final_k<<<dim3(BATCH), 512, 0, stream>>>(
        h0cat, wih_l1r, bih_l1r, bhh_l1r, hst2, fc_w, fc_b, out);
}

// Round 3
// 2826.886 us; speedup vs baseline: 1.0815x; 1.0815x over previous
//
#include <hip/hip_runtime.h>
#include <cstdint>
#include <cstddef>

// Problem constants
#define T_SEQ 512
#define BATCH 128
#define HID   128
#define G4    512      // 4*H
#define NCLS  10

__device__ __forceinline__ float sigmoidf_(float x) {
    return 1.f / (1.f + __expf(-x));
}
__device__ __forceinline__ float tanhf_(float x) {
    return 2.f / (1.f + __expf(-2.f * x)) - 1.f;
}

// ---------------------------------------------------------------------------
// Chunked GEMM (NT): out[m*512+n] = sum_k A[row(m)][k] * W[n][k] + bih[n]+bhh[n]
// m -> (b = m>>tcshift, tt = m&(Tc-1)); global row = b*T_SEQ + tc0 + tt;
// physical A row = rows ? rows[grow] : grow (token gather for layer 0).
// ---------------------------------------------------------------------------
#define BM 128
#define BN 128
#define BK 8

__global__ __launch_bounds__(256)
void gemm_xg(const float* __restrict__ A, const int* __restrict__ rows, int lda,
             const float* __restrict__ W, int K,
             const float* __restrict__ bih, const float* __restrict__ bhh,
             float* __restrict__ out, int tcshift, int tc0)
{
    const int ntn = G4 / BN;              // 4
    int tn = blockIdx.x % ntn;
    int tm = blockIdx.x / ntn;
    int m0 = tm * BM, n0 = tn * BN;
    int tid = threadIdx.x;

    __shared__ __align__(16) float As[BK][BM + 4];
    __shared__ __align__(16) float Ws[BK][BN + 4];

    int lr = tid >> 1;
    int lk = (tid & 1) * 4;

    const float* arow;
    {
        int m  = m0 + lr;
        int b  = m >> tcshift;
        int tt = m & ((1 << tcshift) - 1);
        int grow = b * T_SEQ + tc0 + tt;
        int r = rows ? rows[grow] : grow;
        arow = A + (size_t)r * lda;
    }
    const float* wrow = W + (size_t)(n0 + lr) * K;

    int tx = tid & 15, ty = tid >> 4;
    float acc[8][8];
#pragma unroll
    for (int i = 0; i < 8; i++)
#pragma unroll
        for (int j = 0; j < 8; j++) acc[i][j] = 0.f;

    int nch = (K + BK - 1) / BK;
    for (int ch = 0; ch < nch; ch++) {
        int k0 = ch * BK;
#pragma unroll
        for (int u = 0; u < 4; u++) {
            int k = k0 + lk + u;
            As[lk + u][lr] = (k < K) ? arow[k] : 0.f;
            Ws[lk + u][lr] = (k < K) ? wrow[k] : 0.f;
        }
        __syncthreads();
#pragma unroll
        for (int kk = 0; kk < BK; kk++) {
            float a[8], b[8];
#pragma unroll
            for (int i = 0; i < 8; i++) a[i] = As[kk][ty * 8 + i];
#pragma unroll
            for (int j = 0; j < 8; j++) b[j] = Ws[kk][tx * 8 + j];
#pragma unroll
            for (int i = 0; i < 8; i++)
#pragma unroll
                for (int j = 0; j < 8; j++) acc[i][j] += a[i] * b[j];
        }
        __syncthreads();
    }

#pragma unroll
    for (int j = 0; j < 8; j++) {
        int n = n0 + tx * 8 + j;
        float bv = bih[n] + bhh[n];
#pragma unroll
        for (int i = 0; i < 8; i++) {
            int m = m0 + ty * 8 + i;
            out[(size_t)m * G4 + n] = acc[i][j] + bv;
        }
    }
}

// ---------------------------------------------------------------------------
// LSTM recurrence, split-K lane-pair layout.
// 256 threads/WG, one WG per (dir,b). Lane pair (2q, 2q+1) owns hidden unit q:
// both threads hold w_hh rows {q, q+128, q+256, q+384} restricted to their
// k-half [64p, 64p+64) (256 weight VGPRs), read only their h half from LDS
// (16 ds_read_b128, all-lane 2-address broadcast = free), and reduce partials
// with __shfl_xor(1). Even lane finalizes i,f; odd finalizes g,o; two more
// shuffles bring g,o to the even lane which updates (c,h). h double-buffered
// in LDS -> ONE barrier per step. xg prefetched one step ahead.
// MODE 0: fused l0 fwd+rev (grid 256; dir = wg>>7), writes h0cat.
// MODE 1: single forward dir (grid 128), state only.
// ---------------------------------------------------------------------------
template <int MODE>
__global__ __launch_bounds__(256, 1)
void lstm_rec(const float* __restrict__ xg0, const float* __restrict__ xg1,
              const float* __restrict__ whh_f, const float* __restrict__ whh_r,
              float* __restrict__ hout,
              float* __restrict__ hst_f, float* __restrict__ cst_f,
              float* __restrict__ hst_r, float* __restrict__ cst_r,
              int Tc, int tc0f, int tc0r, int first)
{
    const int wg  = blockIdx.x;
    const int dir = (MODE == 0) ? (wg >> 7) : 0;
    const int b   = wg & 127;
    const float* xgb = (dir ? xg1 : xg0) + (size_t)b * Tc * G4;
    const float* whh = dir ? whh_r : whh_f;
    float* hst = dir ? hst_r : hst_f;
    float* cst = dir ? cst_r : cst_f;
    const int tc0 = dir ? tc0r : tc0f;

    const int j = threadIdx.x;
    const int q = j >> 1;       // hidden unit
    const int p = j & 1;        // k-half / role (0: i,f finalizer; 1: g,o)
    const int r0 = q + p * 256; // xg row for vA (i or g)
    const int r1 = r0 + 128;    // xg row for vB (f or o)

    // Weights: rows q, q+128, q+256, q+384, cols [64p, 64p+64)
    float wI[64], wF[64], wG[64], wO[64];
    {
        const float* bi = whh + (size_t)q * HID + p * 64;
        const float* bf = whh + (size_t)(q + 128) * HID + p * 64;
        const float* bg = whh + (size_t)(q + 256) * HID + p * 64;
        const float* bo = whh + (size_t)(q + 384) * HID + p * 64;
#pragma unroll
        for (int k = 0; k < 64; k += 4) {
            float4 t;
            t = *(const float4*)(bi + k); wI[k]=t.x; wI[k+1]=t.y; wI[k+2]=t.z; wI[k+3]=t.w;
            t = *(const float4*)(bf + k); wF[k]=t.x; wF[k+1]=t.y; wF[k+2]=t.z; wF[k+3]=t.w;
            t = *(const float4*)(bg + k); wG[k]=t.x; wG[k+1]=t.y; wG[k+2]=t.z; wG[k+3]=t.w;
            t = *(const float4*)(bo + k); wO[k]=t.x; wO[k+1]=t.y; wO[k+2]=t.z; wO[k+3]=t.w;
        }
    }

    __shared__ __align__(16) float h_s[2][HID];
    float c_reg = 0.f;
    float hv = 0.f;
    if (j < HID) h_s[0][j] = first ? 0.f : hst[(size_t)b * HID + j];
    if (p == 0 && !first) c_reg = cst[(size_t)b * HID + q];
    __syncthreads();

    int buf = 0;
    // prefetch step 0's xg
    int tt0 = dir ? (Tc - 1) : 0;
    float xvA, xvB;
    {
        const float* xp = xgb + (size_t)tt0 * G4;
        xvA = xp[r0];
        xvB = xp[r1];
    }

    for (int s = 0; s < Tc; s++) {
        int tt = dir ? (Tc - 1 - s) : s;
        // issue next step's xg load (independent of this step's compute)
        float nA = 0.f, nB = 0.f;
        if (s + 1 < Tc) {
            int ttn = dir ? (tt - 1) : (tt + 1);
            const float* xn = xgb + (size_t)ttn * G4;
            nA = xn[r0];
            nB = xn[r1];
        }

        // half-K matvec: 4 independent chains over h_s[buf][64p .. 64p+63]
        const float* hb = &h_s[buf][p * 64];
        float aI = 0.f, aF = 0.f, aG = 0.f, aO = 0.f;
#pragma unroll
        for (int k4 = 0; k4 < 16; k4++) {
            float4 h4 = *(const float4*)(hb + k4 * 4);
            int k = k4 * 4;
            aI += wI[k] * h4.x; aF += wF[k] * h4.x; aG += wG[k] * h4.x; aO += wO[k] * h4.x;
            aI += wI[k+1] * h4.y; aF += wF[k+1] * h4.y; aG += wG[k+1] * h4.y; aO += wO[k+1] * h4.y;
            aI += wI[k+2] * h4.z; aF += wF[k+2] * h4.z; aG += wG[k+2] * h4.z; aO += wO[k+2] * h4.z;
            aI += wI[k+3] * h4.w; aF += wF[k+3] * h4.w; aG += wG[k+3] * h4.w; aO += wO[k+3] * h4.w;
        }

        // cross-lane partial reduction within the pair
        float sA = p ? aI : aG;            // send the half the partner finalizes
        float sB = p ? aF : aO;
        float rA = __shfl_xor(sA, 1, 64);  // even gets odd's aI; odd gets even's aG
        float rB = __shfl_xor(sB, 1, 64);
        float vA = (p ? aG : aI) + rA + xvA;   // even: i-row; odd: g-row
        float vB = (p ? aO : aF) + rB + xvB;   // even: f-row; odd: o-row

        // nonlinearity: vA is sigmoid on even (i), tanh on odd (g); vB sigmoid
        float argA = p ? (2.f * vA) : vA;
        float eA = 1.f / (1.f + __expf(-argA));
        float gA = p ? (2.f * eA - 1.f) : eA;
        float gB = 1.f / (1.f + __expf(-vB));

        // bring odd's (g,o) to the even lane
        float g_g = __shfl_xor(gA, 1, 64);
        float g_o = __shfl_xor(gB, 1, 64);

        if (p == 0) {
            c_reg = gB * c_reg + gA * g_g;          // c = f*c + i*g
            float th = 2.f / (1.f + __expf(-2.f * c_reg)) - 1.f;
            hv = g_o * th;                           // h = o * tanh(c)
            h_s[buf ^ 1][q] = hv;
            if (MODE == 0) {
                int t = tc0 + tt;
                hout[((size_t)b * T_SEQ + t) * 256 + dir * HID + q] = hv;
            }
        }
        __syncthreads();
        buf ^= 1;
        xvA = nA;
        xvB = nB;
    }

    if (p == 0) {
        hst[(size_t)b * HID + q] = hv;
        cst[(size_t)b * HID + q] = c_reg;
    }
}

// ---------------------------------------------------------------------------
// Finale: layer-1 reverse LSTM's t=T-1 output is a SINGLE step from zero
// state (reverse scan processes t=T-1 first), then the FC head.
// ---------------------------------------------------------------------------
__global__ __launch_bounds__(512)
void final_k(const float* __restrict__ h0cat,
             const float* __restrict__ w_ih_r,
             const float* __restrict__ bih_r, const float* __restrict__ bhh_r,
             const float* __restrict__ h1f_last,
             const float* __restrict__ fc_w,
             const float* __restrict__ fc_b,
             float* __restrict__ out)
{
    int b = blockIdx.x;
    int j = threadIdx.x;  // 0..511
    __shared__ __align__(16) float hin[256];
    __shared__ __align__(16) float g_s[G4];
    __shared__ __align__(16) float hcat[256];

    if (j < 256) hin[j] = h0cat[((size_t)b * T_SEQ + (T_SEQ - 1)) * 256 + j];
    __syncthreads();

    float acc = bih_r[j] + bhh_r[j];
    const float* wr = w_ih_r + (size_t)j * 256;
#pragma unroll 8
    for (int k = 0; k < 256; k += 4) {
        float4 h4 = *(const float4*)&hin[k];
        float4 w4 = *(const float4*)&wr[k];
        acc += w4.x * h4.x + w4.y * h4.y + w4.z * h4.z + w4.w * h4.w;
    }
    float v = (j >= 256 && j < 384) ? tanhf_(acc) : sigmoidf_(acc);
    g_s[j] = v;
    if (j < 128) hcat[j] = h1f_last[(size_t)b * HID + j];
    __syncthreads();

    if (j < 128) {
        float gi = g_s[j], gg = g_s[j + 256], go = g_s[j + 384];
        float c = gi * gg;  // f * c0 with c0 = 0
        hcat[128 + j] = go * tanhf_(c);
    }
    __syncthreads();

    if (j < NCLS) {
        float a = fc_b[j];
        const float* fw = fc_w + (size_t)j * 256;
        for (int k = 0; k < 256; k++) a += fw[k] * hcat[k];
        out[(size_t)b * NCLS + j] = a;
    }
}

// ---------------------------------------------------------------------------
// Workspace layout:
//   [0, 64Mi)            h0cat [B][T][256]
//   [64Mi, +384Ki)       6 state slots (h,c) x {l0f, l0r, l1f}
//   [base, +2*chunk)     xgc0, xgc1 : two [B][Tc][512] chunk buffers
// Tc = largest power of two (<=256) such that both chunks fit ws_size.
// ---------------------------------------------------------------------------
extern "C" void kernel_launch(void* const* d_in, const int* in_sizes, int n_in,
                              void* d_out, int out_size, void* d_ws, size_t ws_size,
                              hipStream_t stream)
{
    (void)in_sizes; (void)n_in; (void)out_size;

    const int*   x       = (const int*)  d_in[0];
    const float* emb     = (const float*)d_in[1];
    const float* wih_l0f = (const float*)d_in[2];
    const float* whh_l0f = (const float*)d_in[3];
    const float* bih_l0f = (const float*)d_in[4];
    const float* bhh_l0f = (const float*)d_in[5];
    const float* wih_l0r = (const float*)d_in[6];
    const float* whh_l0r = (const float*)d_in[7];
    const float* bih_l0r = (const float*)d_in[8];
    const float* bhh_l0r = (const float*)d_in[9];
    const float* wih_l1f = (const float*)d_in[10];
    const float* whh_l1f = (const float*)d_in[11];
    const float* bih_l1f = (const float*)d_in[12];
    const float* bhh_l1f = (const float*)d_in[13];
    const float* wih_l1r = (const float*)d_in[14];
    const float* whh_l1r = (const float*)d_in[15];  // unused (single step, h0=c0=0)
    const float* bih_l1r = (const float*)d_in[16];
    const float* bhh_l1r = (const float*)d_in[17];
    const float* fc_w    = (const float*)d_in[18];
    const float* fc_b    = (const float*)d_in[19];
    float* out = (float*)d_out;
    (void)whh_l1r;

    char* ws = (char*)d_ws;
    float* h0cat = (float*)ws;
    float* st    = (float*)(ws + (size_t)67108864);
    float* hst0 = st + 0 * 16384;
    float* cst0 = st + 1 * 16384;
    float* hst1 = st + 2 * 16384;
    float* cst1 = st + 3 * 16384;
    float* hst2 = st + 4 * 16384;
    float* cst2 = st + 5 * 16384;
    const size_t base = (size_t)67108864 + 393216;

    // chunk buffer bytes = B*Tc*512*4 = Tc * 262144
    int Tc = 256;
    while (Tc > 32 && base + 2 * (size_t)262144 * Tc > ws_size) Tc >>= 1;
    const int NC = T_SEQ / Tc;
    int tcshift = 0;
    while ((1 << tcshift) < Tc) tcshift++;
    float* xgc0 = (float*)(ws + base);
    float* xgc1 = xgc0 + (size_t)BATCH * Tc * G4;

    const dim3 gemm_grid(Tc * (G4 / BN));  // (M/BM)*(512/BN), M = 128*Tc

    // Phase 1: layer-0 fwd+rev fused (fwd chunks ascend, rev chunks descend)
    for (int i = 0; i < NC; i++) {
        int cf = i, cr = NC - 1 - i;
        gemm_xg<<<gemm_grid, 256, 0, stream>>>(
            emb, x, 300, wih_l0f, 300, bih_l0f, bhh_l0f, xgc0, tcshift, cf * Tc);
        gemm_xg<<<gemm_grid, 256, 0, stream>>>(
            emb, x, 300, wih_l0r, 300, bih_l0r, bhh_l0r, xgc1, tcshift, cr * Tc);
        lstm_rec<0><<<dim3(2 * BATCH), 256, 0, stream>>>(
            xgc0, xgc1, whh_l0f, whh_l0r, h0cat,
            hst0, cst0, hst1, cst1, Tc, cf * Tc, cr * Tc, i == 0);
    }

    // Phase 2: layer-1 forward (state only)
    for (int i = 0; i < NC; i++) {
        gemm_xg<<<gemm_grid, 256, 0, stream>>>(
            h0cat, nullptr, 256, wih_l1f, 256, bih_l1f, bhh_l1f, xgc0, tcshift, i * Tc);
        lstm_rec<1><<<dim3(BATCH), 256, 0, stream>>>(
            xgc0, nullptr, whh_l1f, nullptr, nullptr,
            hst2, cst2, nullptr, nullptr, Tc, i * Tc, 0, i == 0);
    }

    // Phase 3: layer-1 reverse single step + FC head
    final_k<<<dim3(BATCH), 512, 0, stream>>>(
        h0cat, wih_l1r, bih_l1r, bhh_l1r, hst2, fc_w, fc_b, out);
}

// Round 4
// 2047.234 us; speedup vs baseline: 1.4934x; 1.3808x over previous
//
#include <hip/hip_runtime.h>
#include <cstdint>
#include <cstddef>

// Problem constants
#define T_SEQ 512
#define BATCH 128
#define HID   128
#define G4    512      // 4*H
#define NCLS  10

__device__ __forceinline__ float sigmoidf_(float x) {
    return 1.f / (1.f + __expf(-x));
}
__device__ __forceinline__ float tanhf_(float x) {
    return 2.f / (1.f + __expf(-2.f * x)) - 1.f;
}

// ---------------------------------------------------------------------------
// Chunked GEMM (NT): out[m*512+n] = sum_k A[row(m)][k] * W[n][k] + bih[n]+bhh[n]
// m -> (b = m>>tcshift, tt = m&(Tc-1)); global row = b*T_SEQ + tc0 + tt;
// physical A row = rows ? rows[grow] : grow (token gather for layer 0).
// ---------------------------------------------------------------------------
#define BM 128
#define BN 128
#define BK 8

__global__ __launch_bounds__(256)
void gemm_xg(const float* __restrict__ A, const int* __restrict__ rows, int lda,
             const float* __restrict__ W, int K,
             const float* __restrict__ bih, const float* __restrict__ bhh,
             float* __restrict__ out, int tcshift, int tc0)
{
    const int ntn = G4 / BN;              // 4
    int tn = blockIdx.x % ntn;
    int tm = blockIdx.x / ntn;
    int m0 = tm * BM, n0 = tn * BN;
    int tid = threadIdx.x;

    __shared__ __align__(16) float As[BK][BM + 4];
    __shared__ __align__(16) float Ws[BK][BN + 4];

    int lr = tid >> 1;
    int lk = (tid & 1) * 4;

    const float* arow;
    {
        int m  = m0 + lr;
        int b  = m >> tcshift;
        int tt = m & ((1 << tcshift) - 1);
        int grow = b * T_SEQ + tc0 + tt;
        int r = rows ? rows[grow] : grow;
        arow = A + (size_t)r * lda;
    }
    const float* wrow = W + (size_t)(n0 + lr) * K;

    int tx = tid & 15, ty = tid >> 4;
    float acc[8][8];
#pragma unroll
    for (int i = 0; i < 8; i++)
#pragma unroll
        for (int j = 0; j < 8; j++) acc[i][j] = 0.f;

    int nch = (K + BK - 1) / BK;
    for (int ch = 0; ch < nch; ch++) {
        int k0 = ch * BK;
#pragma unroll
        for (int u = 0; u < 4; u++) {
            int k = k0 + lk + u;
            As[lk + u][lr] = (k < K) ? arow[k] : 0.f;
            Ws[lk + u][lr] = (k < K) ? wrow[k] : 0.f;
        }
        __syncthreads();
#pragma unroll
        for (int kk = 0; kk < BK; kk++) {
            float a[8], b[8];
#pragma unroll
            for (int i = 0; i < 8; i++) a[i] = As[kk][ty * 8 + i];
#pragma unroll
            for (int j = 0; j < 8; j++) b[j] = Ws[kk][tx * 8 + j];
#pragma unroll
            for (int i = 0; i < 8; i++)
#pragma unroll
                for (int j = 0; j < 8; j++) acc[i][j] += a[i] * b[j];
        }
        __syncthreads();
    }

#pragma unroll
    for (int j = 0; j < 8; j++) {
        int n = n0 + tx * 8 + j;
        float bv = bih[n] + bhh[n];
#pragma unroll
        for (int i = 0; i < 8; i++) {
            int m = m0 + ty * 8 + i;
            out[(size_t)m * G4 + n] = acc[i][j] + bv;
        }
    }
}

// ---------------------------------------------------------------------------
// LSTM recurrence, quad-interleaved gate layout (spill-free by construction).
// 512 threads/WG, one WG per (dir,b). Thread j: unit u=j>>2, gate g=j&3,
// owns w_hh row g*128+u entirely (128 weight VGPRs — fits; VGPR cap 256 via
// __launch_bounds__(512,2)). h broadcast from LDS (wave-uniform addresses ->
// free). The 4 gates of unit u sit on 4 ADJACENT LANES of one wave: combine
// via __shfl(width=4), c replicated across the quad, no LDS gate array,
// h double-buffered -> ONE barrier per step. xg prefetched one step ahead.
// MODE 0: fused l0 fwd+rev (grid 256; dir = wg>>7), writes h0cat.
// MODE 1: single forward dir (grid 128), state only.
// ---------------------------------------------------------------------------
template <int MODE>
__global__ __launch_bounds__(512, 2)
void lstm_rec(const float* __restrict__ xg0, const float* __restrict__ xg1,
              const float* __restrict__ whh_f, const float* __restrict__ whh_r,
              float* __restrict__ hout,
              float* __restrict__ hst_f, float* __restrict__ cst_f,
              float* __restrict__ hst_r, float* __restrict__ cst_r,
              int Tc, int tc0f, int tc0r, int first)
{
    const int wg  = blockIdx.x;
    const int dir = (MODE == 0) ? (wg >> 7) : 0;
    const int b   = wg & 127;
    const float* xgb = (dir ? xg1 : xg0) + (size_t)b * Tc * G4;
    const float* whh = dir ? whh_r : whh_f;
    float* hst = dir ? hst_r : hst_f;
    float* cst = dir ? cst_r : cst_f;
    const int tc0 = dir ? tc0r : tc0f;

    const int j = threadIdx.x;   // 0..511
    const int u = j >> 2;        // hidden unit
    const int g = j & 3;         // gate: 0=i 1=f 2=g(tanh) 3=o
    const int row = g * HID + u; // row in w_hh and xg

    float w[128];
    {
        const float* wr = whh + (size_t)row * HID;
#pragma unroll
        for (int k = 0; k < 128; k += 4) {
            float4 t = *(const float4*)(wr + k);
            w[k] = t.x; w[k + 1] = t.y; w[k + 2] = t.z; w[k + 3] = t.w;
        }
    }

    __shared__ __align__(16) float h_s[2][HID];
    float c_rep = 0.f;           // replicated across the 4 lanes of the quad
    if (j < HID) h_s[0][j] = first ? 0.f : hst[(size_t)b * HID + j];
    if (!first) c_rep = cst[(size_t)b * HID + u];
    __syncthreads();

    const float mg = (g == 2) ? 2.f : 1.f;  // tanh(a) = 2/(1+e^-2a)-1

    int buf = 0;
    float xv = xgb[(size_t)(dir ? Tc - 1 : 0) * G4 + row];
    float hlast = 0.f;

    for (int s = 0; s < Tc; s++) {
        const int tt = dir ? (Tc - 1 - s) : s;
        float nxv = 0.f;
        if (s + 1 < Tc) {
            int ttn = dir ? (tt - 1) : (tt + 1);
            nxv = xgb[(size_t)ttn * G4 + row];
        }

        // matvec over full h (wave-uniform LDS reads = broadcast, free);
        // 4 accumulator chains to stay issue-bound, not latency-bound.
        const float* hb = h_s[buf];
        float a0 = 0.f, a1 = 0.f, a2 = 0.f, a3 = 0.f;
#pragma unroll
        for (int k4 = 0; k4 < 32; k4++) {
            float4 h4 = *(const float4*)(hb + k4 * 4);
            int k = k4 * 4;
            a0 += w[k]     * h4.x;
            a1 += w[k + 1] * h4.y;
            a2 += w[k + 2] * h4.z;
            a3 += w[k + 3] * h4.w;
        }
        float a = xv + (a0 + a1) + (a2 + a3);

        // branch-free: sigmoid for g in {0,1,3}, tanh for g==2
        float e = __expf(-mg * a);
        float v = mg / (1.f + e) - (mg - 1.f);

        // quad exchange: every lane gets all four gate values
        float vi = __shfl(v, 0, 4);
        float vf = __shfl(v, 1, 4);
        float vg = __shfl(v, 2, 4);
        float vo = __shfl(v, 3, 4);

        c_rep = vf * c_rep + vi * vg;
        float th = 2.f / (1.f + __expf(-2.f * c_rep)) - 1.f;
        float hv = vo * th;
        hlast = hv;

        if (g == 0) {
            h_s[buf ^ 1][u] = hv;
            if (MODE == 0)
                hout[((size_t)b * T_SEQ + (tc0 + tt)) * 256 + dir * HID + u] = hv;
        }
        __syncthreads();
        buf ^= 1;
        xv = nxv;
    }

    if (g == 0) {
        hst[(size_t)b * HID + u] = hlast;
        cst[(size_t)b * HID + u] = c_rep;
    }
}

// ---------------------------------------------------------------------------
// Finale: layer-1 reverse LSTM's t=T-1 output is a SINGLE step from zero
// state (reverse scan processes t=T-1 first), then the FC head.
// ---------------------------------------------------------------------------
__global__ __launch_bounds__(512)
void final_k(const float* __restrict__ h0cat,
             const float* __restrict__ w_ih_r,
             const float* __restrict__ bih_r, const float* __restrict__ bhh_r,
             const float* __restrict__ h1f_last,
             const float* __restrict__ fc_w,
             const float* __restrict__ fc_b,
             float* __restrict__ out)
{
    int b = blockIdx.x;
    int j = threadIdx.x;  // 0..511
    __shared__ __align__(16) float hin[256];
    __shared__ __align__(16) float g_s[G4];
    __shared__ __align__(16) float hcat[256];

    if (j < 256) hin[j] = h0cat[((size_t)b * T_SEQ + (T_SEQ - 1)) * 256 + j];
    __syncthreads();

    float acc = bih_r[j] + bhh_r[j];
    const float* wr = w_ih_r + (size_t)j * 256;
#pragma unroll 8
    for (int k = 0; k < 256; k += 4) {
        float4 h4 = *(const float4*)&hin[k];
        float4 w4 = *(const float4*)&wr[k];
        acc += w4.x * h4.x + w4.y * h4.y + w4.z * h4.z + w4.w * h4.w;
    }
    float v = (j >= 256 && j < 384) ? tanhf_(acc) : sigmoidf_(acc);
    g_s[j] = v;
    if (j < 128) hcat[j] = h1f_last[(size_t)b * HID + j];
    __syncthreads();

    if (j < 128) {
        float gi = g_s[j], gg = g_s[j + 256], go = g_s[j + 384];
        float c = gi * gg;  // f * c0 with c0 = 0
        hcat[128 + j] = go * tanhf_(c);
    }
    __syncthreads();

    if (j < NCLS) {
        float a = fc_b[j];
        const float* fw = fc_w + (size_t)j * 256;
        for (int k = 0; k < 256; k++) a += fw[k] * hcat[k];
        out[(size_t)b * NCLS + j] = a;
    }
}

// ---------------------------------------------------------------------------
// Workspace layout:
//   [0, 64Mi)            h0cat [B][T][256]
//   [64Mi, +384Ki)       6 state slots (h,c) x {l0f, l0r, l1f}
//   [base, +2*chunk)     xgc0, xgc1 : two [B][Tc][512] chunk buffers
// Tc = largest power of two (<=256) such that both chunks fit ws_size.
// ---------------------------------------------------------------------------
extern "C" void kernel_launch(void* const* d_in, const int* in_sizes, int n_in,
                              void* d_out, int out_size, void* d_ws, size_t ws_size,
                              hipStream_t stream)
{
    (void)in_sizes; (void)n_in; (void)out_size;

    const int*   x       = (const int*)  d_in[0];
    const float* emb     = (const float*)d_in[1];
    const float* wih_l0f = (const float*)d_in[2];
    const float* whh_l0f = (const float*)d_in[3];
    const float* bih_l0f = (const float*)d_in[4];
    const float* bhh_l0f = (const float*)d_in[5];
    const float* wih_l0r = (const float*)d_in[6];
    const float* whh_l0r = (const float*)d_in[7];
    const float* bih_l0r = (const float*)d_in[8];
    const float* bhh_l0r = (const float*)d_in[9];
    const float* wih_l1f = (const float*)d_in[10];
    const float* whh_l1f = (const float*)d_in[11];
    const float* bih_l1f = (const float*)d_in[12];
    const float* bhh_l1f = (const float*)d_in[13];
    const float* wih_l1r = (const float*)d_in[14];
    const float* whh_l1r = (const float*)d_in[15];  // unused (single step, h0=c0=0)
    const float* bih_l1r = (const float*)d_in[16];
    const float* bhh_l1r = (const float*)d_in[17];
    const float* fc_w    = (const float*)d_in[18];
    const float* fc_b    = (const float*)d_in[19];
    float* out = (float*)d_out;
    (void)whh_l1r;

    char* ws = (char*)d_ws;
    float* h0cat = (float*)ws;
    float* st    = (float*)(ws + (size_t)67108864);
    float* hst0 = st + 0 * 16384;
    float* cst0 = st + 1 * 16384;
    float* hst1 = st + 2 * 16384;
    float* cst1 = st + 3 * 16384;
    float* hst2 = st + 4 * 16384;
    float* cst2 = st + 5 * 16384;
    const size_t base = (size_t)67108864 + 393216;

    // chunk buffer bytes = B*Tc*512*4 = Tc * 262144
    int Tc = 256;
    while (Tc > 32 && base + 2 * (size_t)262144 * Tc > ws_size) Tc >>= 1;
    const int NC = T_SEQ / Tc;
    int tcshift = 0;
    while ((1 << tcshift) < Tc) tcshift++;
    float* xgc0 = (float*)(ws + base);
    float* xgc1 = xgc0 + (size_t)BATCH * Tc * G4;

    const dim3 gemm_grid(Tc * (G4 / BN));  // (M/BM)*(512/BN), M = 128*Tc

    // Phase 1: layer-0 fwd+rev fused (fwd chunks ascend, rev chunks descend)
    for (int i = 0; i < NC; i++) {
        int cf = i, cr = NC - 1 - i;
        gemm_xg<<<gemm_grid, 256, 0, stream>>>(
            emb, x, 300, wih_l0f, 300, bih_l0f, bhh_l0f, xgc0, tcshift, cf * Tc);
        gemm_xg<<<gemm_grid, 256, 0, stream>>>(
            emb, x, 300, wih_l0r, 300, bih_l0r, bhh_l0r, xgc1, tcshift, cr * Tc);
        lstm_rec<0><<<dim3(2 * BATCH), 512, 0, stream>>>(
            xgc0, xgc1, whh_l0f, whh_l0r, h0cat,
            hst0, cst0, hst1, cst1, Tc, cf * Tc, cr * Tc, i == 0);
    }

    // Phase 2: layer-1 forward (state only)
    for (int i = 0; i < NC; i++) {
        gemm_xg<<<gemm_grid, 256, 0, stream>>>(
            h0cat, nullptr, 256, wih_l1f, 256, bih_l1f, bhh_l1f, xgc0, tcshift, i * Tc);
        lstm_rec<1><<<dim3(BATCH), 512, 0, stream>>>(
            xgc0, nullptr, whh_l1f, nullptr, nullptr,
            hst2, cst2, nullptr, nullptr, Tc, i * Tc, 0, i == 0);
    }

    // Phase 3: layer-1 reverse single step + FC head
    final_k<<<dim3(BATCH), 512, 0, stream>>>(
        h0cat, wih_l1r, bih_l1r, bhh_l1r, hst2, fc_w, fc_b, out);
}